// Round 16
// baseline (219.053 us; speedup 1.0000x reference)
//
#include <hip/hip_runtime.h>
#include <cstdint>
#include <cstddef>

#define Bv 4
#define Sv 2048
#define Hv 16
#define Dv 1024
#define Mv (Bv*Sv)   // 8192

typedef __attribute__((ext_vector_type(8))) short short8;
typedef __attribute__((ext_vector_type(8))) unsigned short ushort8v;
typedef __attribute__((ext_vector_type(4))) float f32x4;

__device__ inline float bf2f(unsigned short u) {
  union { unsigned int i; float f; } x; x.i = ((unsigned int)u) << 16; return x.f;
}
__device__ inline unsigned short f2bf(float f) {
  union { float f; unsigned int i; } x; x.f = f;
  unsigned int r = x.i + 0x7FFFu + ((x.i >> 16) & 1u);
  return (unsigned short)(r >> 16);
}

typedef __attribute__((address_space(1))) const unsigned short gu16;
typedef __attribute__((address_space(3))) unsigned short lu16;
__device__ inline void gld_lds16(const unsigned short* g, unsigned short* l) {
  __builtin_amdgcn_global_load_lds((gu16*)g, (lu16*)l, 16, 0, 0);
}

// ---------------- fused prelude: x/wqkv/wo cvt + RoPE table in ONE launch ----------------
__global__ __launch_bounds__(256) void prep_all(
    const float* __restrict__ x, const float* __restrict__ wq,
    const float* __restrict__ wk, const float* __restrict__ wv,
    const float* __restrict__ wo, const int* __restrict__ pos,
    unsigned short* __restrict__ xb, unsigned short* __restrict__ wqkvb,
    unsigned short* __restrict__ wob, float* __restrict__ tab) {
  const int bb = blockIdx.x, tid = threadIdx.x;
  if (bb < 8192) {                      // x: 2,097,152 float4
    int i = bb * 256 + tid;
    float4 v = reinterpret_cast<const float4*>(x)[i];
    ushort4 o;
    o.x = f2bf(v.x); o.y = f2bf(v.y); o.z = f2bf(v.z); o.w = f2bf(v.w);
    reinterpret_cast<ushort4*>(xb)[i] = o;
  } else if (bb < 11264) {              // wq|wk|wv -> contiguous [3072][1024]
    int i = (bb - 8192) * 256 + tid;
    int w = i >> 18, off = i & 262143;
    const float* src = (w == 0) ? wq : (w == 1) ? wk : wv;
    float4 v = reinterpret_cast<const float4*>(src)[off];
    ushort4 o;
    o.x = f2bf(v.x); o.y = f2bf(v.y); o.z = f2bf(v.z); o.w = f2bf(v.w);
    reinterpret_cast<ushort4*>(wqkvb)[i] = o;
  } else if (bb < 12288) {              // wo
    int i = (bb - 11264) * 256 + tid;
    float4 v = reinterpret_cast<const float4*>(wo)[i];
    ushort4 o;
    o.x = f2bf(v.x); o.y = f2bf(v.y); o.z = f2bf(v.z); o.w = f2bf(v.w);
    reinterpret_cast<ushort4*>(wob)[i] = o;
  } else {                              // RoPE cos/sin table
    int idx = (bb - 12288) * 256 + tid;  // Sv*32
    int s = idx >> 5, i = idx & 31;
    float p = (float)pos[s];
    float a = p * __builtin_exp2f(-0.41524101186092027f * (float)i);
    tab[(s << 6) + i]      = __builtin_cosf(a);
    tab[(s << 6) + 32 + i] = __builtin_sinf(a);
  }
}

// bijective XCD-chunk swizzle (T1, m204): valid when nwg % 8 == 0
__device__ __forceinline__ void xcd_swizzle(int& bm, int& bn) {
  const int nx = gridDim.x;
  const int nwg = nx * gridDim.y;
  int flat = blockIdx.y * nx + blockIdx.x;
  if ((nwg & 7) == 0) {
    int q = nwg >> 3;
    flat = (flat & 7) * q + (flat >> 3);
  }
  bm = (flat / nx) * 128;
  bn = (flat % nx) * 128;
}

// ---------------- bf16 GEMM (BK=64, XOR-swizzled LDS, r15 structure) — used for wo ------
__device__ inline void storeC(float* p, float v) { *p = v; }
__device__ inline void storeC(unsigned short* p, float v) { *p = f2bf(v); }

template <typename CT>
__global__ __launch_bounds__(256) void gemm_bt_128(
    const unsigned short* __restrict__ A,
    const unsigned short* __restrict__ B,
    CT* __restrict__ C,
    int M, int N, int K) {
  __shared__ unsigned short As[128 * 64];
  __shared__ unsigned short Bs[128 * 64];
  const int tid = threadIdx.x;
  const int wave = tid >> 6, lane = tid & 63;
  int bm, bn;
  xcd_swizzle(bm, bn);
  const int wr = (wave >> 1) * 64, wc = (wave & 1) * 64;

  f32x4 acc[4][4] = {};

  int srow[4], scol[4];
#pragma unroll
  for (int i = 0; i < 4; ++i) {
    int c = i * 4 + wave;
    srow[i] = c * 8 + (lane >> 3);
    scol[i] = ((lane & 7) ^ ((lane >> 3) & 7)) * 8;
  }

  const int fr = lane & 15;
  const int g_ = lane >> 4;
  int offA[2][4], offB[2][4];
#pragma unroll
  for (int kh = 0; kh < 2; ++kh)
#pragma unroll
    for (int m = 0; m < 4; ++m) {
      offA[kh][m] = (wr + m * 16 + fr) * 64 + ((((kh << 2) + g_) ^ (fr & 7)) * 8);
      offB[kh][m] = (wc + m * 16 + fr) * 64 + ((((kh << 2) + g_) ^ (fr & 7)) * 8);
    }

  const int nt = K >> 6;
  auto STAGE = [&](int t) {
    const int k0 = t << 6;
#pragma unroll
    for (int i = 0; i < 4; ++i) {
      gld_lds16(A + (size_t)(bm + srow[i]) * K + k0 + scol[i], &As[(i * 4 + wave) * 512]);
      gld_lds16(B + (size_t)(bn + srow[i]) * K + k0 + scol[i], &Bs[(i * 4 + wave) * 512]);
    }
  };

  STAGE(0);
  __syncthreads();

  for (int t = 0; t < nt; ++t) {
    short8 af[4], bfr[4];
#pragma unroll
    for (int m = 0; m < 4; m++)
      af[m] = *reinterpret_cast<const short8*>(&As[offA[0][m]]);
#pragma unroll
    for (int n = 0; n < 4; n++)
      bfr[n] = *reinterpret_cast<const short8*>(&Bs[offB[0][n]]);
#pragma unroll
    for (int m = 0; m < 4; m++)
#pragma unroll
      for (int n = 0; n < 4; n++)
        acc[m][n] = __builtin_amdgcn_mfma_f32_16x16x32_bf16(af[m], bfr[n], acc[m][n], 0, 0, 0);
    short8 af1[4], bf1[4];
#pragma unroll
    for (int m = 0; m < 4; m++)
      af1[m] = *reinterpret_cast<const short8*>(&As[offA[1][m]]);
#pragma unroll
    for (int n = 0; n < 4; n++)
      bf1[n] = *reinterpret_cast<const short8*>(&Bs[offB[1][n]]);
    __syncthreads();
    if (t + 1 < nt) STAGE(t + 1);
#pragma unroll
    for (int m = 0; m < 4; m++)
#pragma unroll
      for (int n = 0; n < 4; n++)
        acc[m][n] = __builtin_amdgcn_mfma_f32_16x16x32_bf16(af1[m], bf1[n], acc[m][n], 0, 0, 0);
    __syncthreads();
  }

  const int er = (lane >> 4) * 4, ec = lane & 15;
#pragma unroll
  for (int m = 0; m < 4; m++)
#pragma unroll
    for (int n = 0; n < 4; n++)
#pragma unroll
      for (int r = 0; r < 4; r++) {
        int row = bm + wr + m * 16 + er + r;
        int col = bn + wc + n * 16 + ec;
        storeC(&C[(size_t)row * N + col], acc[m][n][r]);
      }
}

// ---------------- fused QKV GEMM: 256x256 tile, 4-phase pipelined K-loop ----------------
// 512 thr = 8 waves (2M x 4N); per-wave output 128x64 (acc f32x4[8][4]).
// LDS 128KB: 2 K-tile buffers, each A[256][64]+B[256][64] bf16, r12-verified XOR swizzle.
// Per K-tile: 4 phases {8 ds_read (quadrant mh,kk) | stage 1 half-tile of t+1 ->
// raw s_barrier -> 16 MFMA (setprio) -> raw s_barrier}; vmcnt(0)+sched_barrier only at
// phase 3 (once per 64 MFMA). WAR: buf[cur^1] last read before tile t-1's closing
// barrier. RAW: boundary vmcnt+barrier certifies tile t+1. Barrier counts wave-uniform.
__global__ __launch_bounds__(512, 2) void gemm_qkv_256(
    const unsigned short* __restrict__ A,
    const unsigned short* __restrict__ Bw,
    unsigned short* __restrict__ Qp,
    unsigned short* __restrict__ Kp,
    unsigned short* __restrict__ Vt,
    const float* __restrict__ tab) {
  const int K = Dv;                      // 1024
  __shared__ unsigned short As[2][16384];  // [256][64] x2 = 64KB
  __shared__ unsigned short Bs[2][16384];  // 64KB -> 128KB total
  const int tid = threadIdx.x;
  const int wave = tid >> 6, lane = tid & 63;
  const int wm = wave >> 2, wn = wave & 3;
  int flat = blockIdx.x;                 // 384 blocks
  flat = (flat & 7) * 48 + (flat >> 3);  // bijective XCD chunk (384/8=48)
  const int bm = (flat / 12) * 256;
  const int bn = (flat % 12) * 256;
  const int wr = wm * 128, wc = wn * 64;

  f32x4 acc[8][4] = {};

  // staging: half-tile = 128 rows x 64 cols of one matrix = 16 chunks x 1KB;
  // chunk = i*8+wave; slot s = chunk*64+lane; src row = s>>3, src granule pre-swizzled.
  const int scolS = ((lane & 7) ^ (lane >> 3)) * 8;   // independent of i/wave
  int srowS[2];
#pragma unroll
  for (int i = 0; i < 2; ++i) srowS[i] = (i * 8 + wave) * 8 + (lane >> 3);

  const int fr = lane & 15;
  const int g_ = lane >> 4;
  int colp[2];                            // swizzled read granule per kk
#pragma unroll
  for (int kk = 0; kk < 2; ++kk) colp[kk] = (((kk << 2) + g_) ^ (fr & 7)) * 8;
  int rowA[8], rowB[4];
#pragma unroll
  for (int mi = 0; mi < 8; ++mi) rowA[mi] = (wr + mi * 16 + fr) * 64;
#pragma unroll
  for (int n = 0; n < 4; ++n) rowB[n] = (wc + n * 16 + fr) * 64;

  auto STAGE_HALF = [&](int h, int t, int b) {
    const int k0 = t << 6;
    const unsigned short* src;
    unsigned short* dst;
    int rowbase;
    if (h < 2) { src = A;  rowbase = bm + h * 128;       dst = &As[b][h * 8192]; }
    else       { src = Bw; rowbase = bn + (h - 2) * 128; dst = &Bs[b][(h - 2) * 8192]; }
#pragma unroll
    for (int i = 0; i < 2; ++i)
      gld_lds16(src + (size_t)(rowbase + srowS[i]) * K + k0 + scolS,
                dst + (i * 8 + wave) * 512);
  };

  const int nkt = K >> 6;                 // 16
  // prologue: stage K-tile 0 fully into buf 0 (8 loads/thread), full drain once
#pragma unroll
  for (int h = 0; h < 4; ++h) STAGE_HALF(h, 0, 0);
  __syncthreads();
  int cur = 0;

  for (int t = 0; t < nkt; ++t) {
    const bool more = (t + 1 < nkt);
#pragma unroll
    for (int p = 0; p < 4; ++p) {
      const int mh = p >> 1, kk = p & 1;
      short8 af[4], bf[4];
#pragma unroll
      for (int j = 0; j < 4; ++j)
        af[j] = *reinterpret_cast<const short8*>(&As[cur][rowA[mh * 4 + j] + colp[kk]]);
#pragma unroll
      for (int n = 0; n < 4; ++n)
        bf[n] = *reinterpret_cast<const short8*>(&Bs[cur][rowB[n] + colp[kk]]);
      if (more) STAGE_HALF(p, t + 1, cur ^ 1);   // 2 loads into the other buffer
      __builtin_amdgcn_s_barrier();              // phase stagger (raw)
      __builtin_amdgcn_s_setprio(1);
#pragma unroll
      for (int j = 0; j < 4; ++j)
#pragma unroll
        for (int n = 0; n < 4; ++n)
          acc[mh * 4 + j][n] =
              __builtin_amdgcn_mfma_f32_16x16x32_bf16(af[j], bf[n], acc[mh * 4 + j][n], 0, 0, 0);
      __builtin_amdgcn_s_setprio(0);
      if (p == 3 && more) {
        asm volatile("s_waitcnt vmcnt(0)" ::: "memory");  // tile t+1 resident (own loads)
        __builtin_amdgcn_sched_barrier(0);
      }
      __builtin_amdgcn_s_barrier();              // closing barrier (certifies cross-wave)
    }
    cur ^= 1;
  }

  // epilogue: RoPE for Q/K regions, transposed store for V
  const int er = (lane >> 4) * 4, ec = lane & 15;
  const int region = bn >> 10;              // block-uniform (256 | 1024)
  if (region < 2) {
    unsigned short* T = (region == 0) ? Qp : Kp;
#pragma unroll
    for (int mi = 0; mi < 8; mi++)
#pragma unroll
      for (int n = 0; n < 4; n++) {
        const int col = bn + wc + n * 16 + ec;
        const int ccol = col & (Dv - 1);
        const int ii = (ccol & 63) >> 1;
        const bool odd = col & 1;
#pragma unroll
        for (int r = 0; r < 4; r++) {
          int row = bm + wr + mi * 16 + er + r;
          int s = row & (Sv - 1);
          float v = acc[mi][n][r];
          float pv = __shfl_xor(v, 1);    // paired feature lives in lane^1 (ec^1)
          float cc = tab[(s << 6) + ii];
          float sn = tab[(s << 6) + 32 + ii];
          float o = odd ? __builtin_fmaf(pv, sn, v * cc)
                        : __builtin_fmaf(v, cc, -(pv * sn));
          T[(size_t)row * Dv + ccol] = f2bf(o);
        }
      }
  } else {
#pragma unroll
    for (int mi = 0; mi < 8; mi++)
#pragma unroll
      for (int n = 0; n < 4; n++) {
        const int dfull = (bn - 2048) + wc + n * 16 + ec;  // h*64+d
        const int row0 = bm + wr + mi * 16 + er;           // 4 consecutive rows, same b
        const int bb = row0 >> 11, s = row0 & (Sv - 1);
        const size_t vtrow = ((size_t)bb * 16 + (dfull >> 6)) * 64 + (dfull & 63);
        ushort4 ov;
        ov.x = f2bf(acc[mi][n][0]);
        ov.y = f2bf(acc[mi][n][1]);
        ov.z = f2bf(acc[mi][n][2]);
        ov.w = f2bf(acc[mi][n][3]);
        *reinterpret_cast<ushort4*>(Vt + vtrow * Sv + s) = ov;
      }
  }
}

// ---------------- MFMA flash attention helpers (32-row strips) ----------------
// S^T layout per strip: lane (g=lane>>4, m=lane&15) holds S^T[k=16*kf+4g+r][q=qf*16+m].
template <bool MASKED>
__device__ __forceinline__ void softmax_strip(
    f32x4 (&sacc)[2][4], const int qrel0,
    float (&mrun2)[2], float (&lrun)[2], f32x4 (&oacc)[2][4],
    unsigned int (&pk)[2][4][2]) {
  const float c1 = 0.18033688011112042f;  // log2(e)/8  (scale = 1/sqrt(64))
#pragma unroll
  for (int qf = 0; qf < 2; ++qf) {
    const int qrel = qrel0 + qf * 16;
    float pv[4][4];
    float mx = -INFINITY;
#pragma unroll
    for (int kf = 0; kf < 4; ++kf)
#pragma unroll
      for (int r = 0; r < 4; ++r) {
        float s = sacc[qf][kf][r];
        if (MASKED) s = (kf * 16 + r > qrel) ? -INFINITY : s;
        pv[kf][r] = s;
        mx = fmaxf(mx, s);
      }
    mx = fmaxf(mx, __shfl_xor(mx, 16));
    mx = fmaxf(mx, __shfl_xor(mx, 32));
    float pm = mx * c1;
    if (__any(pm > mrun2[qf] + 8.0f)) {  // defer-max (T13)
      float m2 = fmaxf(mrun2[qf], pm);
      float sfq = __builtin_exp2f(mrun2[qf] - m2);
      lrun[qf] *= sfq;
#pragma unroll
      for (int dc = 0; dc < 4; ++dc)
#pragma unroll
        for (int r = 0; r < 4; ++r) oacc[qf][dc][r] *= sfq;
      mrun2[qf] = m2;
    }
    const float nm = -mrun2[qf];
    float ps = 0.f;
#pragma unroll
    for (int kf = 0; kf < 4; ++kf)
#pragma unroll
      for (int r = 0; r < 4; ++r) {
        float p = __builtin_exp2f(__builtin_fmaf(pv[kf][r], c1, nm));
        ps += p;
        pv[kf][r] = p;
      }
    ps += __shfl_xor(ps, 16);
    ps += __shfl_xor(ps, 32);
    lrun[qf] += ps;
#pragma unroll
    for (int kf = 0; kf < 4; ++kf)
#pragma unroll
      for (int hh = 0; hh < 2; ++hh) {
        unsigned int rr;
        asm("v_cvt_pk_bf16_f32 %0, %1, %2"
            : "=v"(rr) : "v"(pv[kf][2 * hh]), "v"(pv[kf][2 * hh + 1]));
        pk[qf][kf][hh] = rr;
      }
  }
}

// P^T B-frags via ds_bpermute: word t of target (g',m) = pk[2ks+(g'>>1)][t&1]
// from source lane 16*(2(g'&1)+(t>>1)) + m.
__device__ __forceinline__ void pv_strip(
    const short8 (&vfr)[2][4], const unsigned int (&pk)[2][4][2],
    f32x4 (&oacc)[2][4], const int idx0, const int idx1, const bool hi) {
#pragma unroll
  for (int ks = 0; ks < 2; ++ks)
#pragma unroll
    for (int qf = 0; qf < 2; ++qf) {
      int ra = __builtin_amdgcn_ds_bpermute(idx0, (int)pk[qf][2 * ks][0]);
      int rb = __builtin_amdgcn_ds_bpermute(idx0, (int)pk[qf][2 * ks + 1][0]);
      int rc = __builtin_amdgcn_ds_bpermute(idx0, (int)pk[qf][2 * ks][1]);
      int rd = __builtin_amdgcn_ds_bpermute(idx0, (int)pk[qf][2 * ks + 1][1]);
      int re = __builtin_amdgcn_ds_bpermute(idx1, (int)pk[qf][2 * ks][0]);
      int rf = __builtin_amdgcn_ds_bpermute(idx1, (int)pk[qf][2 * ks + 1][0]);
      int rg = __builtin_amdgcn_ds_bpermute(idx1, (int)pk[qf][2 * ks][1]);
      int rh = __builtin_amdgcn_ds_bpermute(idx1, (int)pk[qf][2 * ks + 1][1]);
      union { unsigned int u[4]; short8 v; } pw;
      pw.u[0] = hi ? (unsigned)rb : (unsigned)ra;
      pw.u[1] = hi ? (unsigned)rd : (unsigned)rc;
      pw.u[2] = hi ? (unsigned)rf : (unsigned)re;
      pw.u[3] = hi ? (unsigned)rh : (unsigned)rg;
      __builtin_amdgcn_s_setprio(1);
#pragma unroll
      for (int dc = 0; dc < 4; ++dc)
        oacc[qf][dc] = __builtin_amdgcn_mfma_f32_16x16x32_bf16(vfr[ks][dc], pw.v, oacc[qf][dc], 0, 0, 0);
      __builtin_amdgcn_s_setprio(0);
    }
}

// ---------------- MFMA flash attention (causal), 32-row paired strips -------------
// r12 structure EXACT (best known: ~99.5us): triple-buffered staging, counted
// vmcnt(4), raw barrier, XCD-affine bh mapping, masked-last-tile peel, 256thr/128VGPR.
__global__ __launch_bounds__(256, 2) void attn_mfma(
    const unsigned short* __restrict__ Q,
    const unsigned short* __restrict__ K,
    const unsigned short* __restrict__ Vt,
    unsigned short* __restrict__ O) {
  __shared__ __align__(16) unsigned short ldsK[3][4096];  // 3 x 8KB (64x64 bf16, swizzled)
  __shared__ __align__(16) unsigned short ldsV[3][4096];
  const int tid = threadIdx.x;
  const int wave = tid >> 6, lane = tid & 63;
  const int g = lane >> 4, m = lane & 15;
  const int F = blockIdx.x;                  // 0..511
  const int q7 = F >> 3;
  const int bh = ((F & 7) << 3) | (q7 & 7);  // XCD-affine (r8: FETCH 131->25MB)
  const int bi = q7 >> 3;                    // 0..7 strip group
  const int b = bh >> 4, h = bh & 15;
  const int j = bi * 4 + wave;               // 0..31
  const int sA = j, sB = 63 - j;
  const int qA0 = sA * 32, qB0 = sB * 32;
  const int ntA = (sA >> 1) + 1, ntB = (sB >> 1) + 1;   // ntB > ntA
  const int ntBmax = ((63 - bi * 4) >> 1) + 1;          // block-uniform, >= 18
  const size_t qkbase = ((size_t)b * Sv) * Dv + (size_t)h * 64;
  const size_t vtbase = (size_t)bh * 64 * Sv;
  const f32x4 zf = {0.f, 0.f, 0.f, 0.f};

  int srowS[2], scolS[2];
#pragma unroll
  for (int i = 0; i < 2; ++i) {
    int s = ((i * 4 + wave) << 6) + lane;
    int s2 = s ^ ((s >> 3) & 7);
    srowS[i] = s2 >> 3;
    scolS[i] = (s2 & 7) * 8;
  }

  short8 qA[2][2], qB[2][2];
#pragma unroll
  for (int qf = 0; qf < 2; ++qf)
#pragma unroll
    for (int ks = 0; ks < 2; ++ks) {
      qA[qf][ks] = *reinterpret_cast<const short8*>(
          Q + qkbase + (size_t)(qA0 + qf * 16 + m) * Dv + ks * 32 + g * 8);
      qB[qf][ks] = *reinterpret_cast<const short8*>(
          Q + qkbase + (size_t)(qB0 + qf * 16 + m) * Dv + ks * 32 + g * 8);
    }

  int offL[2][4];
#pragma unroll
  for (int ks = 0; ks < 2; ++ks)
#pragma unroll
    for (int f = 0; f < 4; ++f)
      offL[ks][f] = (f * 16 + m) * 64 + ((((ks << 2) + g) ^ (m & 7)) * 8);

  f32x4 oA[2][4] = {}, oB[2][4] = {};
  float mA[2] = {-INFINITY, -INFINITY}, mB[2] = {-INFINITY, -INFINITY};
  float lA[2] = {0.f, 0.f}, lB[2] = {0.f, 0.f};

  const int idx0 = (((g & 1) << 5) + m) << 2;
  const int idx1 = idx0 + 64;
  const bool hi = (g >= 2);
  int qrelA = qA0 + m - 4 * g;
  int qrelB = qB0 + m - 4 * g;

  auto STAGE = [&](int c, int t) {
    const int kb = t << 6;
#pragma unroll
    for (int i = 0; i < 2; ++i) {
      gld_lds16(K + qkbase + (size_t)(kb + srowS[i]) * Dv + scolS[i],
                &ldsK[c][(i * 4 + wave) * 512]);
      gld_lds16(Vt + vtbase + (size_t)srowS[i] * Sv + kb + scolS[i],
                &ldsV[c][(i * 4 + wave) * 512]);
    }
  };

  STAGE(0, 0);
  STAGE(1, 1);          // ntBmax >= 18 always
  int cur = 0, bs = 2;

  for (int t = 0; t < ntBmax; ++t) {
    if (t + 1 < ntBmax) {
      asm volatile("s_waitcnt vmcnt(4)" ::: "memory");
    } else {
      asm volatile("s_waitcnt vmcnt(0)" ::: "memory");
    }
    __builtin_amdgcn_sched_barrier(0);
    __builtin_amdgcn_s_barrier();      // raw barrier: no vmcnt drain (T4)
    if (t + 2 < ntBmax) STAGE(bs, t + 2);

    if (t < ntB) {
      const bool actA = (t < ntA);
      f32x4 sAacc[2][4], sBacc[2][4];
      short8 kfr[4];
#pragma unroll
      for (int kf = 0; kf < 4; ++kf)
        kfr[kf] = *reinterpret_cast<const short8*>(&ldsK[cur][offL[0][kf]]);
      __builtin_amdgcn_s_setprio(1);
#pragma unroll
      for (int qf = 0; qf < 2; ++qf)
#pragma unroll
        for (int kf = 0; kf < 4; ++kf)
          sBacc[qf][kf] = __builtin_amdgcn_mfma_f32_16x16x32_bf16(kfr[kf], qB[qf][0], zf, 0, 0, 0);
      if (actA)
#pragma unroll
        for (int qf = 0; qf < 2; ++qf)
#pragma unroll
          for (int kf = 0; kf < 4; ++kf)
            sAacc[qf][kf] = __builtin_amdgcn_mfma_f32_16x16x32_bf16(kfr[kf], qA[qf][0], zf, 0, 0, 0);
      __builtin_amdgcn_s_setprio(0);
#pragma unroll
      for (int kf = 0; kf < 4; ++kf)
        kfr[kf] = *reinterpret_cast<const short8*>(&ldsK[cur][offL[1][kf]]);
      __builtin_amdgcn_s_setprio(1);
#pragma unroll
      for (int qf = 0; qf < 2; ++qf)
#pragma unroll
        for (int kf = 0; kf < 4; ++kf)
          sBacc[qf][kf] = __builtin_amdgcn_mfma_f32_16x16x32_bf16(kfr[kf], qB[qf][1], sBacc[qf][kf], 0, 0, 0);
      if (actA)
#pragma unroll
        for (int qf = 0; qf < 2; ++qf)
#pragma unroll
          for (int kf = 0; kf < 4; ++kf)
            sAacc[qf][kf] = __builtin_amdgcn_mfma_f32_16x16x32_bf16(kfr[kf], qA[qf][1], sAacc[qf][kf], 0, 0, 0);
      __builtin_amdgcn_s_setprio(0);

      short8 vfr[2][4];
#pragma unroll
      for (int ks = 0; ks < 2; ++ks)
#pragma unroll
        for (int dc = 0; dc < 4; ++dc)
          vfr[ks][dc] = *reinterpret_cast<const short8*>(&ldsV[cur][offL[ks][dc]]);

      unsigned int pkB[2][4][2], pkA[2][4][2];
      if (t == ntB - 1) softmax_strip<true >(sBacc, qrelB, mB, lB, oB, pkB);
      else              softmax_strip<false>(sBacc, qrelB, mB, lB, oB, pkB);
      if (actA) {
        if (t == ntA - 1) softmax_strip<true >(sAacc, qrelA, mA, lA, oA, pkA);
        else              softmax_strip<false>(sAacc, qrelA, mA, lA, oA, pkA);
      }
      pv_strip(vfr, pkB, oB, idx0, idx1, hi);
      if (actA) pv_strip(vfr, pkA, oA, idx0, idx1, hi);

      qrelA -= 64; qrelB -= 64;
    }

    cur = (cur == 2) ? 0 : cur + 1;
    bs = (bs == 2) ? 0 : bs + 1;
  }

#pragma unroll
  for (int qf = 0; qf < 2; ++qf) {
    float rnA = 1.0f / lA[qf];
    float rnB = 1.0f / lB[qf];
    size_t rowA = (size_t)(qA0 + qf * 16 + m);
    size_t rowB = (size_t)(qB0 + qf * 16 + m);
#pragma unroll
    for (int dc = 0; dc < 4; ++dc) {
      ushort4 ov;
      ov.x = f2bf(oA[qf][dc][0] * rnA);
      ov.y = f2bf(oA[qf][dc][1] * rnA);
      ov.z = f2bf(oA[qf][dc][2] * rnA);
      ov.w = f2bf(oA[qf][dc][3] * rnA);
      *reinterpret_cast<ushort4*>(O + qkbase + rowA * Dv + dc * 16 + 4 * g) = ov;
      ov.x = f2bf(oB[qf][dc][0] * rnB);
      ov.y = f2bf(oB[qf][dc][1] * rnB);
      ov.z = f2bf(oB[qf][dc][2] * rnB);
      ov.w = f2bf(oB[qf][dc][3] * rnB);
      *reinterpret_cast<ushort4*>(O + qkbase + rowB * Dv + dc * 16 + 4 * g) = ov;
    }
  }
}

// ---------------- launcher ----------------
extern "C" void kernel_launch(void* const* d_in, const int* in_sizes, int n_in,
                              void* d_out, int out_size, void* d_ws, size_t ws_size,
                              hipStream_t stream) {
  const float* x   = (const float*)d_in[0];
  const int*   pos = (const int*)d_in[1];
  const float* wq  = (const float*)d_in[2];
  const float* wk  = (const float*)d_in[3];
  const float* wv  = (const float*)d_in[4];
  const float* wo  = (const float*)d_in[5];
  float* out = (float*)d_out;

  char* w = (char*)d_ws;
  unsigned short* xb    = (unsigned short*)(w);               // 16 MB: x bf16, later attn out
  unsigned short* wqkvb = (unsigned short*)(w + (16u << 20)); // 6 MB contiguous [3072][1024]
  unsigned short* wob   = (unsigned short*)(w + (22u << 20)); // 2 MB
  unsigned short* Qp    = (unsigned short*)(w + (24u << 20)); // 16 MB
  unsigned short* Kp    = (unsigned short*)(w + (40u << 20)); // 16 MB
  unsigned short* Vt    = (unsigned short*)(w + (56u << 20)); // 16 MB
  float*          tab   = (float*)(w + (72u << 20));          // 512 KB

  prep_all<<<12544, 256, 0, stream>>>(x, wq, wk, wv, wo, pos, xb, wqkvb, wob, tab);

  // 256x256 4-phase pipelined QKV projection + RoPE + V-transpose (384 blocks, 512 thr)
  gemm_qkv_256<<<384, 512, 0, stream>>>(xb, wqkvb, Qp, Kp, Vt, tab);

  attn_mfma<<<512, 256, 0, stream>>>(Qp, Kp, Vt, xb);

  gemm_bt_128<float><<<dim3(Dv / 128, Mv / 128), 256, 0, stream>>>(xb, wob, out, Mv, Dv, Dv);
}

// Round 17
// 200.469 us; speedup vs baseline: 1.0927x; 1.0927x over previous
//
#include <hip/hip_runtime.h>
#include <cstdint>
#include <cstddef>

#define Bv 4
#define Sv 2048
#define Hv 16
#define Dv 1024
#define Mv (Bv*Sv)   // 8192

typedef __attribute__((ext_vector_type(8))) short short8;
typedef __attribute__((ext_vector_type(8))) unsigned short ushort8v;
typedef __attribute__((ext_vector_type(4))) float f32x4;

__device__ inline float bf2f(unsigned short u) {
  union { unsigned int i; float f; } x; x.i = ((unsigned int)u) << 16; return x.f;
}
__device__ inline unsigned short f2bf(float f) {
  union { float f; unsigned int i; } x; x.f = f;
  unsigned int r = x.i + 0x7FFFu + ((x.i >> 16) & 1u);
  return (unsigned short)(r >> 16);
}

typedef __attribute__((address_space(1))) const unsigned short gu16;
typedef __attribute__((address_space(3))) unsigned short lu16;
__device__ inline void gld_lds16(const unsigned short* g, unsigned short* l) {
  __builtin_amdgcn_global_load_lds((gu16*)g, (lu16*)l, 16, 0, 0);
}

// ---------------- fused prelude: x/wqkv/wo cvt + RoPE table in ONE launch ----------------
__global__ __launch_bounds__(256) void prep_all(
    const float* __restrict__ x, const float* __restrict__ wq,
    const float* __restrict__ wk, const float* __restrict__ wv,
    const float* __restrict__ wo, const int* __restrict__ pos,
    unsigned short* __restrict__ xb, unsigned short* __restrict__ wqkvb,
    unsigned short* __restrict__ wob, float* __restrict__ tab) {
  const int bb = blockIdx.x, tid = threadIdx.x;
  if (bb < 8192) {                      // x: 2,097,152 float4
    int i = bb * 256 + tid;
    float4 v = reinterpret_cast<const float4*>(x)[i];
    ushort4 o;
    o.x = f2bf(v.x); o.y = f2bf(v.y); o.z = f2bf(v.z); o.w = f2bf(v.w);
    reinterpret_cast<ushort4*>(xb)[i] = o;
  } else if (bb < 11264) {              // wq|wk|wv -> contiguous [3072][1024]
    int i = (bb - 8192) * 256 + tid;
    int w = i >> 18, off = i & 262143;
    const float* src = (w == 0) ? wq : (w == 1) ? wk : wv;
    float4 v = reinterpret_cast<const float4*>(src)[off];
    ushort4 o;
    o.x = f2bf(v.x); o.y = f2bf(v.y); o.z = f2bf(v.z); o.w = f2bf(v.w);
    reinterpret_cast<ushort4*>(wqkvb)[i] = o;
  } else if (bb < 12288) {              // wo
    int i = (bb - 11264) * 256 + tid;
    float4 v = reinterpret_cast<const float4*>(wo)[i];
    ushort4 o;
    o.x = f2bf(v.x); o.y = f2bf(v.y); o.z = f2bf(v.z); o.w = f2bf(v.w);
    reinterpret_cast<ushort4*>(wob)[i] = o;
  } else {                              // RoPE cos/sin table
    int idx = (bb - 12288) * 256 + tid;  // Sv*32
    int s = idx >> 5, i = idx & 31;
    float p = (float)pos[s];
    float a = p * __builtin_exp2f(-0.41524101186092027f * (float)i);
    tab[(s << 6) + i]      = __builtin_cosf(a);
    tab[(s << 6) + 32 + i] = __builtin_sinf(a);
  }
}

// bijective XCD-chunk swizzle (T1, m204): valid when nwg % 8 == 0
__device__ __forceinline__ void xcd_swizzle(int& bm, int& bn) {
  const int nx = gridDim.x;
  const int nwg = nx * gridDim.y;
  int flat = blockIdx.y * nx + blockIdx.x;
  if ((nwg & 7) == 0) {
    int q = nwg >> 3;
    flat = (flat & 7) * q + (flat >> 3);
  }
  bm = (flat / nx) * 128;
  bn = (flat % nx) * 128;
}

// ---------------- bf16 GEMM (BK=64, XOR-swizzled LDS, r12-verified offsets) ------------
// C[M,N] = A[M,K] * B[N,K]^T. LDS 128x64 per matrix (32KB total, 4 blocks/CU).
// Reordered K-step: reads+MFMA(kh0) BEFORE the first barrier, STAGE(t+1) AFTER it
// (WAR-safe: barrier certifies all waves' ds_reads done), MFMA(kh1) overlaps staging.
__device__ inline void storeC(float* p, float v) { *p = v; }
__device__ inline void storeC(unsigned short* p, float v) { *p = f2bf(v); }

template <typename CT>
__global__ __launch_bounds__(256) void gemm_bt_128(
    const unsigned short* __restrict__ A,
    const unsigned short* __restrict__ B,
    CT* __restrict__ C,
    int M, int N, int K) {
  __shared__ unsigned short As[128 * 64];
  __shared__ unsigned short Bs[128 * 64];
  const int tid = threadIdx.x;
  const int wave = tid >> 6, lane = tid & 63;
  int bm, bn;
  xcd_swizzle(bm, bn);
  const int wr = (wave >> 1) * 64, wc = (wave & 1) * 64;

  f32x4 acc[4][4] = {};

  // staging: chunk c = i*4+wave covers rows c*8..c*8+7 (8 rows x 64 cols = 512 shorts)
  int srow[4], scol[4];
#pragma unroll
  for (int i = 0; i < 4; ++i) {
    int c = i * 4 + wave;
    srow[i] = c * 8 + (lane >> 3);
    scol[i] = ((lane & 7) ^ ((lane >> 3) & 7)) * 8;
  }

  const int fr = lane & 15;
  const int g_ = lane >> 4;
  int offA[2][4], offB[2][4];
#pragma unroll
  for (int kh = 0; kh < 2; ++kh)
#pragma unroll
    for (int m = 0; m < 4; ++m) {
      offA[kh][m] = (wr + m * 16 + fr) * 64 + ((((kh << 2) + g_) ^ (fr & 7)) * 8);
      offB[kh][m] = (wc + m * 16 + fr) * 64 + ((((kh << 2) + g_) ^ (fr & 7)) * 8);
    }

  const int nt = K >> 6;
  auto STAGE = [&](int t) {
    const int k0 = t << 6;
#pragma unroll
    for (int i = 0; i < 4; ++i) {
      gld_lds16(A + (size_t)(bm + srow[i]) * K + k0 + scol[i], &As[(i * 4 + wave) * 512]);
      gld_lds16(B + (size_t)(bn + srow[i]) * K + k0 + scol[i], &Bs[(i * 4 + wave) * 512]);
    }
  };

  STAGE(0);
  __syncthreads();

  for (int t = 0; t < nt; ++t) {
    short8 af[4], bfr[4];
    // kh0: read + MFMA (frees fragment regs before kh1 loads)
#pragma unroll
    for (int m = 0; m < 4; m++)
      af[m] = *reinterpret_cast<const short8*>(&As[offA[0][m]]);
#pragma unroll
    for (int n = 0; n < 4; n++)
      bfr[n] = *reinterpret_cast<const short8*>(&Bs[offB[0][n]]);
#pragma unroll
    for (int m = 0; m < 4; m++)
#pragma unroll
      for (int n = 0; n < 4; n++)
        acc[m][n] = __builtin_amdgcn_mfma_f32_16x16x32_bf16(af[m], bfr[n], acc[m][n], 0, 0, 0);
    // kh1: read fragments into regs
    short8 af1[4], bf1[4];
#pragma unroll
    for (int m = 0; m < 4; m++)
      af1[m] = *reinterpret_cast<const short8*>(&As[offA[1][m]]);
#pragma unroll
    for (int n = 0; n < 4; n++)
      bf1[n] = *reinterpret_cast<const short8*>(&Bs[offB[1][n]]);
    __syncthreads();                 // all waves' LDS reads of tile t complete
    if (t + 1 < nt) STAGE(t + 1);    // overwrite buffer; latency hides under MFMA kh1
#pragma unroll
    for (int m = 0; m < 4; m++)
#pragma unroll
      for (int n = 0; n < 4; n++)
        acc[m][n] = __builtin_amdgcn_mfma_f32_16x16x32_bf16(af1[m], bf1[n], acc[m][n], 0, 0, 0);
    __syncthreads();                 // drains STAGE(t+1) + release
  }

  const int er = (lane >> 4) * 4, ec = lane & 15;
#pragma unroll
  for (int m = 0; m < 4; m++)
#pragma unroll
    for (int n = 0; n < 4; n++)
#pragma unroll
      for (int r = 0; r < 4; r++) {
        int row = bm + wr + m * 16 + er + r;
        int col = bn + wc + n * 16 + ec;
        storeC(&C[(size_t)row * N + col], acc[m][n][r]);
      }
}

// ---------------- fused QKV GEMM (BK=64, reordered): epilogue RoPE / V-transpose -------
__global__ __launch_bounds__(256) void gemm_qkv(
    const unsigned short* __restrict__ A,
    const unsigned short* __restrict__ B,
    unsigned short* __restrict__ Qp,
    unsigned short* __restrict__ Kp,
    unsigned short* __restrict__ Vt,
    const float* __restrict__ tab) {
  const int K = Dv;
  __shared__ unsigned short As[128 * 64];
  __shared__ unsigned short Bs[128 * 64];
  const int tid = threadIdx.x;
  const int wave = tid >> 6, lane = tid & 63;
  int bm, bn;
  xcd_swizzle(bm, bn);
  const int wr = (wave >> 1) * 64, wc = (wave & 1) * 64;

  f32x4 acc[4][4] = {};

  int srow[4], scol[4];
#pragma unroll
  for (int i = 0; i < 4; ++i) {
    int c = i * 4 + wave;
    srow[i] = c * 8 + (lane >> 3);
    scol[i] = ((lane & 7) ^ ((lane >> 3) & 7)) * 8;
  }

  const int fr = lane & 15;
  const int g_ = lane >> 4;
  int offA[2][4], offB[2][4];
#pragma unroll
  for (int kh = 0; kh < 2; ++kh)
#pragma unroll
    for (int m = 0; m < 4; ++m) {
      offA[kh][m] = (wr + m * 16 + fr) * 64 + ((((kh << 2) + g_) ^ (fr & 7)) * 8);
      offB[kh][m] = (wc + m * 16 + fr) * 64 + ((((kh << 2) + g_) ^ (fr & 7)) * 8);
    }

  const int nt = K >> 6;
  auto STAGE = [&](int t) {
    const int k0 = t << 6;
#pragma unroll
    for (int i = 0; i < 4; ++i) {
      gld_lds16(A + (size_t)(bm + srow[i]) * K + k0 + scol[i], &As[(i * 4 + wave) * 512]);
      gld_lds16(B + (size_t)(bn + srow[i]) * K + k0 + scol[i], &Bs[(i * 4 + wave) * 512]);
    }
  };

  STAGE(0);
  __syncthreads();

  for (int t = 0; t < nt; ++t) {
    short8 af[4], bfr[4];
#pragma unroll
    for (int m = 0; m < 4; m++)
      af[m] = *reinterpret_cast<const short8*>(&As[offA[0][m]]);
#pragma unroll
    for (int n = 0; n < 4; n++)
      bfr[n] = *reinterpret_cast<const short8*>(&Bs[offB[0][n]]);
#pragma unroll
    for (int m = 0; m < 4; m++)
#pragma unroll
      for (int n = 0; n < 4; n++)
        acc[m][n] = __builtin_amdgcn_mfma_f32_16x16x32_bf16(af[m], bfr[n], acc[m][n], 0, 0, 0);
    short8 af1[4], bf1[4];
#pragma unroll
    for (int m = 0; m < 4; m++)
      af1[m] = *reinterpret_cast<const short8*>(&As[offA[1][m]]);
#pragma unroll
    for (int n = 0; n < 4; n++)
      bf1[n] = *reinterpret_cast<const short8*>(&Bs[offB[1][n]]);
    __syncthreads();
    if (t + 1 < nt) STAGE(t + 1);
#pragma unroll
    for (int m = 0; m < 4; m++)
#pragma unroll
      for (int n = 0; n < 4; n++)
        acc[m][n] = __builtin_amdgcn_mfma_f32_16x16x32_bf16(af1[m], bf1[n], acc[m][n], 0, 0, 0);
    __syncthreads();
  }

  const int er = (lane >> 4) * 4, ec = lane & 15;
  const int region = bn >> 10;  // block-uniform: 0=Q, 1=K, 2=V
  if (region < 2) {
    unsigned short* T = (region == 0) ? Qp : Kp;
#pragma unroll
    for (int m = 0; m < 4; m++)
#pragma unroll
      for (int n = 0; n < 4; n++) {
        const int col = bn + wc + n * 16 + ec;
        const int ccol = col & (Dv - 1);
        const int ii = (ccol & 63) >> 1;
        const bool odd = col & 1;
#pragma unroll
        for (int r = 0; r < 4; r++) {
          int row = bm + wr + m * 16 + er + r;
          int s = row & (Sv - 1);
          float v = acc[m][n][r];
          float pv = __shfl_xor(v, 1);  // paired feature lives in lane^1 (ec^1)
          float cc = tab[(s << 6) + ii];
          float sn = tab[(s << 6) + 32 + ii];
          float o = odd ? __builtin_fmaf(pv, sn, v * cc)
                        : __builtin_fmaf(v, cc, -(pv * sn));
          T[(size_t)row * Dv + ccol] = f2bf(o);
        }
      }
  } else {
#pragma unroll
    for (int m = 0; m < 4; m++)
#pragma unroll
      for (int n = 0; n < 4; n++) {
        const int dfull = (bn - 2048) + wc + n * 16 + ec;  // h*64+d
        const int row0 = bm + wr + m * 16 + er;            // 4 consecutive rows (same b)
        const int bb = row0 >> 11, s = row0 & (Sv - 1);
        const size_t vtrow = ((size_t)bb * 16 + (dfull >> 6)) * 64 + (dfull & 63);
        ushort4 ov;
        ov.x = f2bf(acc[m][n][0]);
        ov.y = f2bf(acc[m][n][1]);
        ov.z = f2bf(acc[m][n][2]);
        ov.w = f2bf(acc[m][n][3]);
        *reinterpret_cast<ushort4*>(Vt + vtrow * Sv + s) = ov;
      }
  }
}

// ---------------- MFMA flash attention helpers (32-row strips) ----------------
// S^T layout per strip: lane (g=lane>>4, m=lane&15) holds S^T[k=16*kf+4g+r][q=qf*16+m].
template <bool MASKED>
__device__ __forceinline__ void softmax_strip(
    f32x4 (&sacc)[2][4], const int qrel0,
    float (&mrun2)[2], float (&lrun)[2], f32x4 (&oacc)[2][4],
    unsigned int (&pk)[2][4][2]) {
  const float c1 = 0.18033688011112042f;  // log2(e)/8  (scale = 1/sqrt(64))
#pragma unroll
  for (int qf = 0; qf < 2; ++qf) {
    const int qrel = qrel0 + qf * 16;
    float pv[4][4];
    float mx = -INFINITY;
#pragma unroll
    for (int kf = 0; kf < 4; ++kf)
#pragma unroll
      for (int r = 0; r < 4; ++r) {
        float s = sacc[qf][kf][r];
        if (MASKED) s = (kf * 16 + r > qrel) ? -INFINITY : s;
        pv[kf][r] = s;
        mx = fmaxf(mx, s);
      }
    mx = fmaxf(mx, __shfl_xor(mx, 16));
    mx = fmaxf(mx, __shfl_xor(mx, 32));
    float pm = mx * c1;
    if (__any(pm > mrun2[qf] + 8.0f)) {  // defer-max (T13)
      float m2 = fmaxf(mrun2[qf], pm);
      float sfq = __builtin_exp2f(mrun2[qf] - m2);
      lrun[qf] *= sfq;
#pragma unroll
      for (int dc = 0; dc < 4; ++dc)
#pragma unroll
        for (int r = 0; r < 4; ++r) oacc[qf][dc][r] *= sfq;
      mrun2[qf] = m2;
    }
    const float nm = -mrun2[qf];
    float ps = 0.f;
#pragma unroll
    for (int kf = 0; kf < 4; ++kf)
#pragma unroll
      for (int r = 0; r < 4; ++r) {
        float p = __builtin_exp2f(__builtin_fmaf(pv[kf][r], c1, nm));
        ps += p;
        pv[kf][r] = p;
      }
    ps += __shfl_xor(ps, 16);
    ps += __shfl_xor(ps, 32);
    lrun[qf] += ps;
#pragma unroll
    for (int kf = 0; kf < 4; ++kf)
#pragma unroll
      for (int hh = 0; hh < 2; ++hh) {
        unsigned int rr;
        asm("v_cvt_pk_bf16_f32 %0, %1, %2"
            : "=v"(rr) : "v"(pv[kf][2 * hh]), "v"(pv[kf][2 * hh + 1]));
        pk[qf][kf][hh] = rr;
      }
  }
}

// P^T B-frags via ds_bpermute: word t of target (g',m) = pk[2ks+(g'>>1)][t&1]
// from source lane 16*(2(g'&1)+(t>>1)) + m.
__device__ __forceinline__ void pv_strip(
    const short8 (&vfr)[2][4], const unsigned int (&pk)[2][4][2],
    f32x4 (&oacc)[2][4], const int idx0, const int idx1, const bool hi) {
#pragma unroll
  for (int ks = 0; ks < 2; ++ks)
#pragma unroll
    for (int qf = 0; qf < 2; ++qf) {
      int ra = __builtin_amdgcn_ds_bpermute(idx0, (int)pk[qf][2 * ks][0]);
      int rb = __builtin_amdgcn_ds_bpermute(idx0, (int)pk[qf][2 * ks + 1][0]);
      int rc = __builtin_amdgcn_ds_bpermute(idx0, (int)pk[qf][2 * ks][1]);
      int rd = __builtin_amdgcn_ds_bpermute(idx0, (int)pk[qf][2 * ks + 1][1]);
      int re = __builtin_amdgcn_ds_bpermute(idx1, (int)pk[qf][2 * ks][0]);
      int rf = __builtin_amdgcn_ds_bpermute(idx1, (int)pk[qf][2 * ks + 1][0]);
      int rg = __builtin_amdgcn_ds_bpermute(idx1, (int)pk[qf][2 * ks][1]);
      int rh = __builtin_amdgcn_ds_bpermute(idx1, (int)pk[qf][2 * ks + 1][1]);
      union { unsigned int u[4]; short8 v; } pw;
      pw.u[0] = hi ? (unsigned)rb : (unsigned)ra;
      pw.u[1] = hi ? (unsigned)rd : (unsigned)rc;
      pw.u[2] = hi ? (unsigned)rf : (unsigned)re;
      pw.u[3] = hi ? (unsigned)rh : (unsigned)rg;
      __builtin_amdgcn_s_setprio(1);
#pragma unroll
      for (int dc = 0; dc < 4; ++dc)
        oacc[qf][dc] = __builtin_amdgcn_mfma_f32_16x16x32_bf16(vfr[ks][dc], pw.v, oacc[qf][dc], 0, 0, 0);
      __builtin_amdgcn_s_setprio(0);
    }
}

// ---------------- MFMA flash attention (causal), 32-row paired strips -------------
// r12 structure EXACT (best known: ~99.5us): triple-buffered staging, counted
// vmcnt(4), raw barrier, XCD-affine bh mapping, masked-last-tile peel, 256thr/128VGPR.
__global__ __launch_bounds__(256, 2) void attn_mfma(
    const unsigned short* __restrict__ Q,
    const unsigned short* __restrict__ K,
    const unsigned short* __restrict__ Vt,
    unsigned short* __restrict__ O) {
  __shared__ __align__(16) unsigned short ldsK[3][4096];  // 3 x 8KB (64x64 bf16, swizzled)
  __shared__ __align__(16) unsigned short ldsV[3][4096];
  const int tid = threadIdx.x;
  const int wave = tid >> 6, lane = tid & 63;
  const int g = lane >> 4, m = lane & 15;
  const int F = blockIdx.x;                  // 0..511
  const int q7 = F >> 3;
  const int bh = ((F & 7) << 3) | (q7 & 7);  // XCD-affine (r8: FETCH 131->25MB)
  const int bi = q7 >> 3;                    // 0..7 strip group
  const int b = bh >> 4, h = bh & 15;
  const int j = bi * 4 + wave;               // 0..31
  const int sA = j, sB = 63 - j;
  const int qA0 = sA * 32, qB0 = sB * 32;
  const int ntA = (sA >> 1) + 1, ntB = (sB >> 1) + 1;   // ntB > ntA
  const int ntBmax = ((63 - bi * 4) >> 1) + 1;          // block-uniform, >= 18
  const size_t qkbase = ((size_t)b * Sv) * Dv + (size_t)h * 64;
  const size_t vtbase = (size_t)bh * 64 * Sv;
  const f32x4 zf = {0.f, 0.f, 0.f, 0.f};

  int srowS[2], scolS[2];
#pragma unroll
  for (int i = 0; i < 2; ++i) {
    int s = ((i * 4 + wave) << 6) + lane;
    int s2 = s ^ ((s >> 3) & 7);
    srowS[i] = s2 >> 3;
    scolS[i] = (s2 & 7) * 8;
  }

  short8 qA[2][2], qB[2][2];
#pragma unroll
  for (int qf = 0; qf < 2; ++qf)
#pragma unroll
    for (int ks = 0; ks < 2; ++ks) {
      qA[qf][ks] = *reinterpret_cast<const short8*>(
          Q + qkbase + (size_t)(qA0 + qf * 16 + m) * Dv + ks * 32 + g * 8);
      qB[qf][ks] = *reinterpret_cast<const short8*>(
          Q + qkbase + (size_t)(qB0 + qf * 16 + m) * Dv + ks * 32 + g * 8);
    }

  int offL[2][4];
#pragma unroll
  for (int ks = 0; ks < 2; ++ks)
#pragma unroll
    for (int f = 0; f < 4; ++f)
      offL[ks][f] = (f * 16 + m) * 64 + ((((ks << 2) + g) ^ (m & 7)) * 8);

  f32x4 oA[2][4] = {}, oB[2][4] = {};
  float mA[2] = {-INFINITY, -INFINITY}, mB[2] = {-INFINITY, -INFINITY};
  float lA[2] = {0.f, 0.f}, lB[2] = {0.f, 0.f};

  const int idx0 = (((g & 1) << 5) + m) << 2;
  const int idx1 = idx0 + 64;
  const bool hi = (g >= 2);
  int qrelA = qA0 + m - 4 * g;
  int qrelB = qB0 + m - 4 * g;

  auto STAGE = [&](int c, int t) {
    const int kb = t << 6;
#pragma unroll
    for (int i = 0; i < 2; ++i) {
      gld_lds16(K + qkbase + (size_t)(kb + srowS[i]) * Dv + scolS[i],
                &ldsK[c][(i * 4 + wave) * 512]);
      gld_lds16(Vt + vtbase + (size_t)srowS[i] * Sv + kb + scolS[i],
                &ldsV[c][(i * 4 + wave) * 512]);
    }
  };

  STAGE(0, 0);
  STAGE(1, 1);          // ntBmax >= 18 always
  int cur = 0, bs = 2;

  for (int t = 0; t < ntBmax; ++t) {
    if (t + 1 < ntBmax) {
      asm volatile("s_waitcnt vmcnt(4)" ::: "memory");
    } else {
      asm volatile("s_waitcnt vmcnt(0)" ::: "memory");
    }
    __builtin_amdgcn_sched_barrier(0);
    __builtin_amdgcn_s_barrier();      // raw barrier: no vmcnt drain (T4)
    if (t + 2 < ntBmax) STAGE(bs, t + 2);

    if (t < ntB) {
      const bool actA = (t < ntA);
      f32x4 sAacc[2][4], sBacc[2][4];
      short8 kfr[4];
#pragma unroll
      for (int kf = 0; kf < 4; ++kf)
        kfr[kf] = *reinterpret_cast<const short8*>(&ldsK[cur][offL[0][kf]]);
      __builtin_amdgcn_s_setprio(1);
#pragma unroll
      for (int qf = 0; qf < 2; ++qf)
#pragma unroll
        for (int kf = 0; kf < 4; ++kf)
          sBacc[qf][kf] = __builtin_amdgcn_mfma_f32_16x16x32_bf16(kfr[kf], qB[qf][0], zf, 0, 0, 0);
      if (actA)
#pragma unroll
        for (int qf = 0; qf < 2; ++qf)
#pragma unroll
          for (int kf = 0; kf < 4; ++kf)
            sAacc[qf][kf] = __builtin_amdgcn_mfma_f32_16x16x32_bf16(kfr[kf], qA[qf][0], zf, 0, 0, 0);
      __builtin_amdgcn_s_setprio(0);
#pragma unroll
      for (int kf = 0; kf < 4; ++kf)
        kfr[kf] = *reinterpret_cast<const short8*>(&ldsK[cur][offL[1][kf]]);
      __builtin_amdgcn_s_setprio(1);
#pragma unroll
      for (int qf = 0; qf < 2; ++qf)
#pragma unroll
        for (int kf = 0; kf < 4; ++kf)
          sBacc[qf][kf] = __builtin_amdgcn_mfma_f32_16x16x32_bf16(kfr[kf], qB[qf][1], sBacc[qf][kf], 0, 0, 0);
      if (actA)
#pragma unroll
        for (int qf = 0; qf < 2; ++qf)
#pragma unroll
          for (int kf = 0; kf < 4; ++kf)
            sAacc[qf][kf] = __builtin_amdgcn_mfma_f32_16x16x32_bf16(kfr[kf], qA[qf][1], sAacc[qf][kf], 0, 0, 0);
      __builtin_amdgcn_s_setprio(0);

      short8 vfr[2][4];
#pragma unroll
      for (int ks = 0; ks < 2; ++ks)
#pragma unroll
        for (int dc = 0; dc < 4; ++dc)
          vfr[ks][dc] = *reinterpret_cast<const short8*>(&ldsV[cur][offL[ks][dc]]);

      unsigned int pkB[2][4][2], pkA[2][4][2];
      if (t == ntB - 1) softmax_strip<true >(sBacc, qrelB, mB, lB, oB, pkB);
      else              softmax_strip<false>(sBacc, qrelB, mB, lB, oB, pkB);
      if (actA) {
        if (t == ntA - 1) softmax_strip<true >(sAacc, qrelA, mA, lA, oA, pkA);
        else              softmax_strip<false>(sAacc, qrelA, mA, lA, oA, pkA);
      }
      pv_strip(vfr, pkB, oB, idx0, idx1, hi);
      if (actA) pv_strip(vfr, pkA, oA, idx0, idx1, hi);

      qrelA -= 64; qrelB -= 64;
    }

    cur = (cur == 2) ? 0 : cur + 1;
    bs = (bs == 2) ? 0 : bs + 1;
  }

#pragma unroll
  for (int qf = 0; qf < 2; ++qf) {
    float rnA = 1.0f / lA[qf];
    float rnB = 1.0f / lB[qf];
    size_t rowA = (size_t)(qA0 + qf * 16 + m);
    size_t rowB = (size_t)(qB0 + qf * 16 + m);
#pragma unroll
    for (int dc = 0; dc < 4; ++dc) {
      ushort4 ov;
      ov.x = f2bf(oA[qf][dc][0] * rnA);
      ov.y = f2bf(oA[qf][dc][1] * rnA);
      ov.z = f2bf(oA[qf][dc][2] * rnA);
      ov.w = f2bf(oA[qf][dc][3] * rnA);
      *reinterpret_cast<ushort4*>(O + qkbase + rowA * Dv + dc * 16 + 4 * g) = ov;
      ov.x = f2bf(oB[qf][dc][0] * rnB);
      ov.y = f2bf(oB[qf][dc][1] * rnB);
      ov.z = f2bf(oB[qf][dc][2] * rnB);
      ov.w = f2bf(oB[qf][dc][3] * rnB);
      *reinterpret_cast<ushort4*>(O + qkbase + rowB * Dv + dc * 16 + 4 * g) = ov;
    }
  }
}

// ---------------- launcher ----------------
extern "C" void kernel_launch(void* const* d_in, const int* in_sizes, int n_in,
                              void* d_out, int out_size, void* d_ws, size_t ws_size,
                              hipStream_t stream) {
  const float* x   = (const float*)d_in[0];
  const int*   pos = (const int*)d_in[1];
  const float* wq  = (const float*)d_in[2];
  const float* wk  = (const float*)d_in[3];
  const float* wv  = (const float*)d_in[4];
  const float* wo  = (const float*)d_in[5];
  float* out = (float*)d_out;

  char* w = (char*)d_ws;
  unsigned short* xb    = (unsigned short*)(w);               // 16 MB: x bf16, later attn out
  unsigned short* wqkvb = (unsigned short*)(w + (16u << 20)); // 6 MB contiguous [3072][1024]
  unsigned short* wob   = (unsigned short*)(w + (22u << 20)); // 2 MB
  unsigned short* Qp    = (unsigned short*)(w + (24u << 20)); // 16 MB
  unsigned short* Kp    = (unsigned short*)(w + (40u << 20)); // 16 MB
  unsigned short* Vt    = (unsigned short*)(w + (56u << 20)); // 16 MB
  float*          tab   = (float*)(w + (72u << 20));          // 512 KB

  prep_all<<<12544, 256, 0, stream>>>(x, wq, wk, wv, wo, pos, xb, wqkvb, wob, tab);

  gemm_qkv<<<dim3(3 * Dv / 128, Mv / 128), 256, 0, stream>>>(xb, wqkvb, Qp, Kp, Vt, tab);

  attn_mfma<<<512, 256, 0, stream>>>(Qp, Kp, Vt, xb);

  gemm_bt_128<float><<<dim3(Dv / 128, Mv / 128), 256, 0, stream>>>(xb, wob, out, Mv, Dv, Dv);
}